// Round 5
// baseline (256.592 us; speedup 1.0000x reference)
//
#include <hip/hip_runtime.h>
#include <cstdint>

#define B_DIM 32
#define C_DIM 512
#define N_SP 1024
#define GROUPS 32
#define CPG 16
#define EPS 1e-5f

typedef __attribute__((ext_vector_type(8))) __bf16 bf16x8;
typedef __attribute__((ext_vector_type(4))) __bf16 bf16x4;
typedef __attribute__((ext_vector_type(4))) float f32x4;

__device__ __forceinline__ void gload16(const void* g, void* l) {
    __builtin_amdgcn_global_load_lds(
        (__attribute__((address_space(1))) void*)(unsigned long long)(uintptr_t)g,
        (__attribute__((address_space(3))) void*)(unsigned int)(uintptr_t)l,
        16, 0, 0);
}

// ---------------- GroupNorm stats ----------------
__global__ __launch_bounds__(256) void gn_stats_kernel(const float* __restrict__ x,
                                                       float* __restrict__ stats) {
    int bg = blockIdx.x;
    const float4* p4 = (const float4*)(x + (size_t)bg * (CPG * N_SP));
    int tid = threadIdx.x;
    float s = 0.f, sq = 0.f;
    for (int i = tid; i < (CPG * N_SP) / 4; i += 256) {
        float4 v = p4[i];
        s  += v.x + v.y + v.z + v.w;
        sq += v.x * v.x + v.y * v.y + v.z * v.z + v.w * v.w;
    }
    for (int off = 32; off > 0; off >>= 1) {
        s  += __shfl_xor(s, off);
        sq += __shfl_xor(sq, off);
    }
    __shared__ float ls[4], lq[4];
    int wid = tid >> 6;
    if ((tid & 63) == 0) { ls[wid] = s; lq[wid] = sq; }
    __syncthreads();
    if (tid == 0) {
        s  = ls[0] + ls[1] + ls[2] + ls[3];
        sq = lq[0] + lq[1] + lq[2] + lq[3];
        float mean = s / (float)(CPG * N_SP);
        float var  = sq / (float)(CPG * N_SP) - mean * mean;
        stats[2 * bg]     = mean;
        stats[2 * bg + 1] = rsqrtf(var + EPS);
    }
}

// ------- GroupNorm apply + transpose: x[b][c][n] -> hT[b][n][c] (bf16) -------
__global__ __launch_bounds__(256) void gn_apply_t_kernel(const float* __restrict__ x,
                                                         const float* __restrict__ stats,
                                                         const float* __restrict__ w,
                                                         const float* __restrict__ b,
                                                         __bf16* __restrict__ hT) {
    int bn = blockIdx.x * 64, bc = blockIdx.y * 64, bb = blockIdx.z;
    __shared__ float tile[64][65];
    __shared__ float sw[64], sb[64];
    int t = threadIdx.x;
    if (t < 64) {
        int c = bc + t;
        int g = c / CPG;
        float mean = stats[2 * (bb * GROUPS + g)];
        float rstd = stats[2 * (bb * GROUPS + g) + 1];
        float s = w[c] * rstd;
        sw[t] = s;
        sb[t] = b[c] - mean * s;
    }
    __syncthreads();
    const float* xb = x + ((size_t)bb * C_DIM + bc) * N_SP + bn;
#pragma unroll
    for (int it = 0; it < 4; ++it) {
        int cl = (t >> 4) + 16 * it;
        int n4 = (t & 15) * 4;
        float4 v = *(const float4*)&xb[(size_t)cl * N_SP + n4];
        float s = sw[cl], o = sb[cl];
        tile[cl][n4 + 0] = v.x * s + o;
        tile[cl][n4 + 1] = v.y * s + o;
        tile[cl][n4 + 2] = v.z * s + o;
        tile[cl][n4 + 3] = v.w * s + o;
    }
    __syncthreads();
    __bf16* hb = hT + ((size_t)bb * N_SP + bn) * C_DIM + bc;
    int nl = t >> 2, c16 = (t & 3) * 16;
    bf16x8 o1, o2;
#pragma unroll
    for (int e = 0; e < 8; ++e) o1[e] = (__bf16)tile[c16 + e][nl];
#pragma unroll
    for (int e = 0; e < 8; ++e) o2[e] = (__bf16)tile[c16 + 8 + e][nl];
    *(bf16x8*)&hb[(size_t)nl * C_DIM + c16] = o1;
    *(bf16x8*)&hb[(size_t)nl * C_DIM + c16 + 8] = o2;
}

// ---------------- fp32 -> bf16 conversion (256 blocks x 1024 elems) ----------------
__global__ __launch_bounds__(256) void f2bf_kernel(const float* __restrict__ in,
                                                   __bf16* __restrict__ out) {
    int i = blockIdx.x * 256 + threadIdx.x;
    float4 v = ((const float4*)in)[i];
    bf16x4 o;
    o[0] = (__bf16)v.x; o[1] = (__bf16)v.y; o[2] = (__bf16)v.z; o[3] = (__bf16)v.w;
    ((bf16x4*)out)[i] = o;
}

__global__ __launch_bounds__(256) void pack_qk_bias(const float* __restrict__ qb,
                                                    const float* __restrict__ kb,
                                                    float* __restrict__ o) {
    int i = blockIdx.x * 256 + threadIdx.x;
    o[i] = (i < 512) ? qb[i] : kb[i - 512];
}

// ------- softmax over row of 1024 bf16, in place -------
__global__ __launch_bounds__(256) void softmax_bf16(__bf16* __restrict__ S) {
    __bf16* p = S + (size_t)blockIdx.x * N_SP;
    int tid = threadIdx.x;
    bf16x4 v4 = ((bf16x4*)p)[tid];
    float a = (float)v4[0], b = (float)v4[1], c = (float)v4[2], d = (float)v4[3];
    float m = fmaxf(fmaxf(a, b), fmaxf(c, d));
    for (int off = 32; off > 0; off >>= 1) m = fmaxf(m, __shfl_xor(m, off));
    __shared__ float lm[4], lsum[4];
    int wid = tid >> 6;
    if ((tid & 63) == 0) lm[wid] = m;
    __syncthreads();
    m = fmaxf(fmaxf(lm[0], lm[1]), fmaxf(lm[2], lm[3]));
    a = __expf(a - m); b = __expf(b - m); c = __expf(c - m); d = __expf(d - m);
    float s = a + b + c + d;
    for (int off = 32; off > 0; off >>= 1) s += __shfl_xor(s, off);
    if ((tid & 63) == 0) lsum[wid] = s;
    __syncthreads();
    s = lsum[0] + lsum[1] + lsum[2] + lsum[3];
    float inv = 1.f / s;
    bf16x4 o;
    o[0] = (__bf16)(a * inv); o[1] = (__bf16)(b * inv);
    o[2] = (__bf16)(c * inv); o[3] = (__bf16)(d * inv);
    ((bf16x4*)p)[tid] = o;
}

// ============ 256x256 8-wave GEMM, unit-staged K-tiles with counted vmcnt ============
// C[M][N] = A[M][*] * BT[N][*]^T, bf16 in, fp32 acc. BK=64.
// Stage units (16KB, 2 gloads/thread): A-unit x = rows {x*64..+64} u {128+x*64..+64};
// B-unit y = cols (y-subtiles of all wn). Per tile 4 phases, issue u(t+1,A0/B0/B1/A1)
// at P1..P4; reads P1:{A-x0,B-y0} P2:{B-y1} P3:{A-x1} P4:{}. vmcnt(4) at P1/P2/P4 end
// keeps 2 units in flight; every unit has >=3 phases of flight. No full drain in loop.
// EPI: 0 bf16; 1 bf16+bias[col]; 2 bf16+bias[row]; 4 f32+bias[row]+resid; 5 bf16*scale
#define WAITV(n) asm volatile("s_waitcnt vmcnt(" #n ")" ::: "memory")
#define BAR() __builtin_amdgcn_s_barrier()

template <int M, int N, int K, int LDA, int LDB, int EPI>
__global__ __launch_bounds__(512, 2) void gemm8p(const __bf16* __restrict__ A, size_t sA,
                                                 const __bf16* __restrict__ BT, size_t sB,
                                                 void* __restrict__ Y, size_t sY,
                                                 const float* __restrict__ bias,
                                                 const float* __restrict__ resid, size_t sR,
                                                 float scale) {
    static_assert(M % 256 == 0 && N % 256 == 0 && K % 128 == 0, "shape");
    constexpr int GX = N / 256, GY = M / 256, NT = K / 64;
    __shared__ __align__(16) __bf16 lds[2][2][2][8192];  // [buf][op][unit][128 rows x 64]

    const int tid = threadIdx.x;
    const int w = tid >> 6, lane = tid & 63;
    const int wm = w >> 2, wn = w & 3;
    const int lrow = lane & 15, koct = lane >> 4;

    const int nwg = gridDim.x;
    const int wg = ((int)blockIdx.x & 7) * (nwg >> 3) + ((int)blockIdx.x >> 3);
    const int bz = wg / (GX * GY);
    const int rem = wg - bz * (GX * GY);
    const int bm = (rem / GX) * 256, bn = (rem % GX) * 256;

    const __bf16* Ab = A + (size_t)bz * sA;
    const __bf16* Bb = BT + (size_t)bz * sB;

    // staging: thread covers unit rows (tid>>3) and (tid>>3)+64; source k pre-swizzled
    const int r = tid >> 3;
    const int kswz = ((tid & 7) ^ (r & 7)) * 8;
    const __bf16* srcA = Ab + (size_t)(bm + r) * LDA + kswz;
    const __bf16* srcB = Bb + (size_t)(bn + (r & 31) + ((r >> 5) & 1) * 64) * LDB + kswz;

#define STG_A(buf, x, kt) do { \
    gload16(srcA + (size_t)((x) * 64) * LDA + (size_t)(kt) * 64,       &lds[buf][0][x][w * 512]); \
    gload16(srcA + (size_t)((x) * 64 + 128) * LDA + (size_t)(kt) * 64, &lds[buf][0][x][4096 + w * 512]); \
} while (0)
#define STG_B(buf, y, kt) do { \
    gload16(srcB + (size_t)((y) * 32) * LDB + (size_t)(kt) * 64,       &lds[buf][1][y][w * 512]); \
    gload16(srcB + (size_t)((y) * 32 + 128) * LDB + (size_t)(kt) * 64, &lds[buf][1][y][4096 + w * 512]); \
} while (0)

    // fragment read addressing (read side of the swizzle involution)
    const int ks0 = (koct ^ (lrow & 7)) * 8;
    const int ks1 = ks0 ^ 32;
    const int aoff = (wm * 64 + lrow) * 64;
    const int boff = (wn * 32 + lrow) * 64;

    bf16x8 aF[4][2], bF0[2][2], bF1[2][2];
    f32x4 acc[8][4];
#pragma unroll
    for (int i = 0; i < 8; ++i)
#pragma unroll
        for (int j = 0; j < 4; ++j) acc[i][j] = (f32x4){0.f, 0.f, 0.f, 0.f};

#define RD_A(ct, x) do { _Pragma("unroll") for (int i = 0; i < 4; ++i) { \
    aF[i][0] = *(const bf16x8*)&lds[ct][0][x][aoff + i * 1024 + ks0]; \
    aF[i][1] = *(const bf16x8*)&lds[ct][0][x][aoff + i * 1024 + ks1]; } } while (0)
#define RD_B(BF, ct, y) do { _Pragma("unroll") for (int j = 0; j < 2; ++j) { \
    BF[j][0] = *(const bf16x8*)&lds[ct][1][y][boff + j * 1024 + ks0]; \
    BF[j][1] = *(const bf16x8*)&lds[ct][1][y][boff + j * 1024 + ks1]; } } while (0)

#define MMQ(X, Y, BF) do { \
    __builtin_amdgcn_s_setprio(1); \
    _Pragma("unroll") for (int k = 0; k < 2; ++k) \
    _Pragma("unroll") for (int i = 0; i < 4; ++i) \
    _Pragma("unroll") for (int j = 0; j < 2; ++j) \
        acc[(X) * 4 + i][(Y) * 2 + j] = __builtin_amdgcn_mfma_f32_16x16x32_bf16( \
            aF[i][k], BF[j][k], acc[(X) * 4 + i][(Y) * 2 + j], 0, 0, 0); \
    __builtin_amdgcn_s_setprio(0); \
} while (0)

    // prologue: stage tile 0 fully (4 units), drain once, barrier
    STG_A(0, 0, 0); STG_B(0, 0, 0); STG_B(0, 1, 0); STG_A(0, 1, 0);
    WAITV(0); BAR();

#pragma unroll 1
    for (int t = 0; t < NT - 1; ++t) {
        const int ct = t & 1, nx = ct ^ 1;
        // P1: issue u(t+1,A0); read A-x0 + B-y0; Q00
        STG_A(nx, 0, t + 1);
        RD_A(ct, 0); RD_B(bF0, ct, 0);
        BAR(); MMQ(0, 0, bF0); WAITV(4); BAR();
        // P2: issue u(t+1,B0); read B-y1; Q01
        STG_B(nx, 0, t + 1);
        RD_B(bF1, ct, 1);
        BAR(); MMQ(0, 1, bF1); WAITV(4); BAR();
        // P3: issue u(t+1,B1); read A-x1; Q11
        STG_B(nx, 1, t + 1);
        RD_A(ct, 1);
        BAR(); MMQ(1, 1, bF1); BAR();
        // P4: issue u(t+1,A1); Q10 (frags already live)
        STG_A(nx, 1, t + 1);
        BAR(); MMQ(1, 0, bF0); WAITV(4); BAR();
    }
    {   // tail tile: in-flight on entry = {B1, A1} of this tile
        const int ct = (NT - 1) & 1;
        RD_A(ct, 0); RD_B(bF0, ct, 0);
        BAR(); MMQ(0, 0, bF0); WAITV(2); BAR();
        RD_B(bF1, ct, 1);
        BAR(); MMQ(0, 1, bF1); WAITV(0); BAR();
        RD_A(ct, 1);
        BAR(); MMQ(1, 1, bF1); BAR();
        MMQ(1, 0, bF0);
    }

    // epilogue: C/D layout col=lane&15, row=koct*4+reg
    float* Yf = (float*)Y + (size_t)bz * sY;
    __bf16* Yh = (__bf16*)Y + (size_t)bz * sY;
    const float* Rb = (EPI == 4) ? (resid + (size_t)bz * sR) : nullptr;
#pragma unroll
    for (int i = 0; i < 8; ++i)
#pragma unroll
        for (int rr = 0; rr < 4; ++rr) {
            int grow = bm + wm * 128 + i * 16 + koct * 4 + rr;
            float brv = (EPI == 2 || EPI == 4) ? bias[grow] : 0.f;
#pragma unroll
            for (int j = 0; j < 4; ++j) {
                int gcol = bn + wn * 64 + j * 16 + lrow;
                float vv = acc[i][j][rr];
                if (EPI == 1) vv += bias[gcol];
                if (EPI == 2 || EPI == 4) vv += brv;
                if (EPI == 5) vv *= scale;
                size_t yi = (size_t)grow * N + gcol;
                if (EPI == 4) {
                    Yf[yi] = vv + Rb[yi];
                } else {
                    Yh[yi] = (__bf16)vv;
                }
            }
        }
#undef STG_A
#undef STG_B
#undef RD_A
#undef RD_B
#undef MMQ
}

extern "C" void kernel_launch(void* const* d_in, const int* in_sizes, int n_in,
                              void* d_out, int out_size, void* d_ws, size_t ws_size,
                              hipStream_t stream) {
    const float* x      = (const float*)d_in[0];
    const float* norm_w = (const float*)d_in[1];
    const float* norm_b = (const float*)d_in[2];
    const float* q_w    = (const float*)d_in[3];
    const float* q_b    = (const float*)d_in[4];
    const float* k_w    = (const float*)d_in[5];
    const float* k_b    = (const float*)d_in[6];
    const float* v_w    = (const float*)d_in[7];
    const float* v_b    = (const float*)d_in[8];
    const float* proj_w = (const float*)d_in[9];
    const float* proj_b = (const float*)d_in[10];
    float* out = (float*)d_out;

    const size_t ELEM = (size_t)N_SP * C_DIM;            // 524288
    const size_t QK   = (size_t)N_SP * 1024;             // 1048576
    char* ws = (char*)d_ws;
    __bf16* hT  = (__bf16*)ws;                           // 32MB, reused as Ot
    __bf16* qkT = (__bf16*)(ws + ((size_t)32 << 20));    // 64MB: [b][n][q||k]
    __bf16* wqk = (__bf16*)(ws + ((size_t)96 << 20));    // 1MB  [1024][512]
    __bf16* wv  = (__bf16*)(ws + ((size_t)97 << 20));
    __bf16* wp  = wv + 262144;
    float* qkb  = (float*)(ws + ((size_t)98 << 20));
    float* stats = qkb + 1024;
    size_t sbase = ((size_t)99 << 20);
    __bf16* S = (__bf16*)(ws + sbase);                   // chunk x [1024][1024] bf16
    __bf16* v  = (__bf16*)d_out;                         // V lives in d_out until proj
    __bf16* Ot = hT;

    int chunk = (int)((ws_size - sbase) >> 21);          // 2MB per batch of S
    if (chunk > B_DIM) chunk = B_DIM;
    if (chunk < 1) chunk = 1;

    gn_stats_kernel<<<B_DIM * GROUPS, 256, 0, stream>>>(x, stats);
    gn_apply_t_kernel<<<dim3(16, 8, B_DIM), 256, 0, stream>>>(x, stats, norm_w, norm_b, hT);

    f2bf_kernel<<<256, 256, 0, stream>>>(q_w, wqk);
    f2bf_kernel<<<256, 256, 0, stream>>>(k_w, wqk + 262144);
    f2bf_kernel<<<256, 256, 0, stream>>>(v_w, wv);
    f2bf_kernel<<<256, 256, 0, stream>>>(proj_w, wp);
    pack_qk_bias<<<4, 256, 0, stream>>>(q_b, k_b, qkb);

    // qkT[n][0..1023] = hT[n][:] x (wq||wk)^T + (q_b||k_b)
    gemm8p<1024, 1024, 512, 512, 512, 1><<<512, 512, 0, stream>>>(
        hT, ELEM, wqk, 0, qkT, QK, qkb, nullptr, 0, 1.f);
    // v[oc][n] = wv[oc][:] x hT[n][:] + v_b[oc]
    gemm8p<512, 1024, 512, 512, 512, 2><<<256, 512, 0, stream>>>(
        wv, 0, hT, ELEM, v, ELEM, v_b, nullptr, 0, 1.f);

    const float scale = 0.044194173824159216f;  // 512^-0.5
    for (int b0 = 0; b0 < B_DIM; b0 += chunk) {
        int nb = (b0 + chunk <= B_DIM) ? chunk : (B_DIM - b0);
        // S[i][j] = bf16( scale * sum_c qT[i][c] kT[j][c] )
        gemm8p<1024, 1024, 512, 1024, 1024, 5><<<16 * nb, 512, 0, stream>>>(
            qkT + (size_t)b0 * QK, QK, qkT + (size_t)b0 * QK + 512, QK,
            S, QK, nullptr, nullptr, 0, scale);
        softmax_bf16<<<nb * N_SP, 256, 0, stream>>>(S);
        // Ot[i][c] = sum_j P[i][j] v[c][j]
        gemm8p<1024, 512, 1024, 1024, 1024, 0><<<8 * nb, 512, 0, stream>>>(
            S, QK, v + (size_t)b0 * ELEM, ELEM,
            Ot + (size_t)b0 * ELEM, ELEM, nullptr, nullptr, 0, 1.f);
    }

    // out[oc][n] = wp[oc][:] x Ot[n][:] + proj_b[oc] + x[oc][n]
    gemm8p<512, 1024, 512, 512, 512, 4><<<256, 512, 0, stream>>>(
        wp, 0, Ot, ELEM, out, ELEM, proj_b, x, ELEM, 1.f);
}

// Round 6
// 251.950 us; speedup vs baseline: 1.0184x; 1.0184x over previous
//
#include <hip/hip_runtime.h>
#include <cstdint>

#define B_DIM 32
#define C_DIM 512
#define N_SP 1024
#define GROUPS 32
#define CPG 16
#define EPS 1e-5f

typedef __attribute__((ext_vector_type(8))) __bf16 bf16x8;
typedef __attribute__((ext_vector_type(4))) __bf16 bf16x4;
typedef __attribute__((ext_vector_type(4))) float f32x4;

__device__ __forceinline__ void gload16(const void* g, void* l) {
    __builtin_amdgcn_global_load_lds(
        (__attribute__((address_space(1))) void*)(unsigned long long)(uintptr_t)g,
        (__attribute__((address_space(3))) void*)(unsigned int)(uintptr_t)l,
        16, 0, 0);
}

// ---------------- GroupNorm stats ----------------
__global__ __launch_bounds__(256) void gn_stats_kernel(const float* __restrict__ x,
                                                       float* __restrict__ stats) {
    int bg = blockIdx.x;
    const float4* p4 = (const float4*)(x + (size_t)bg * (CPG * N_SP));
    int tid = threadIdx.x;
    float s = 0.f, sq = 0.f;
    for (int i = tid; i < (CPG * N_SP) / 4; i += 256) {
        float4 v = p4[i];
        s  += v.x + v.y + v.z + v.w;
        sq += v.x * v.x + v.y * v.y + v.z * v.z + v.w * v.w;
    }
    for (int off = 32; off > 0; off >>= 1) {
        s  += __shfl_xor(s, off);
        sq += __shfl_xor(sq, off);
    }
    __shared__ float ls[4], lq[4];
    int wid = tid >> 6;
    if ((tid & 63) == 0) { ls[wid] = s; lq[wid] = sq; }
    __syncthreads();
    if (tid == 0) {
        s  = ls[0] + ls[1] + ls[2] + ls[3];
        sq = lq[0] + lq[1] + lq[2] + lq[3];
        float mean = s / (float)(CPG * N_SP);
        float var  = sq / (float)(CPG * N_SP) - mean * mean;
        stats[2 * bg]     = mean;
        stats[2 * bg + 1] = rsqrtf(var + EPS);
    }
}

// ------- GroupNorm apply + transpose: x[b][c][n] -> hT[b][n][c] (bf16) -------
__global__ __launch_bounds__(256) void gn_apply_t_kernel(const float* __restrict__ x,
                                                         const float* __restrict__ stats,
                                                         const float* __restrict__ w,
                                                         const float* __restrict__ b,
                                                         __bf16* __restrict__ hT) {
    int bn = blockIdx.x * 64, bc = blockIdx.y * 64, bb = blockIdx.z;
    __shared__ float tile[64][65];
    __shared__ float sw[64], sb[64];
    int t = threadIdx.x;
    if (t < 64) {
        int c = bc + t;
        int g = c / CPG;
        float mean = stats[2 * (bb * GROUPS + g)];
        float rstd = stats[2 * (bb * GROUPS + g) + 1];
        float s = w[c] * rstd;
        sw[t] = s;
        sb[t] = b[c] - mean * s;
    }
    __syncthreads();
    const float* xb = x + ((size_t)bb * C_DIM + bc) * N_SP + bn;
#pragma unroll
    for (int it = 0; it < 4; ++it) {
        int cl = (t >> 4) + 16 * it;
        int n4 = (t & 15) * 4;
        float4 v = *(const float4*)&xb[(size_t)cl * N_SP + n4];
        float s = sw[cl], o = sb[cl];
        tile[cl][n4 + 0] = v.x * s + o;
        tile[cl][n4 + 1] = v.y * s + o;
        tile[cl][n4 + 2] = v.z * s + o;
        tile[cl][n4 + 3] = v.w * s + o;
    }
    __syncthreads();
    __bf16* hb = hT + ((size_t)bb * N_SP + bn) * C_DIM + bc;
    int nl = t >> 2, c16 = (t & 3) * 16;
    bf16x8 o1, o2;
#pragma unroll
    for (int e = 0; e < 8; ++e) o1[e] = (__bf16)tile[c16 + e][nl];
#pragma unroll
    for (int e = 0; e < 8; ++e) o2[e] = (__bf16)tile[c16 + 8 + e][nl];
    *(bf16x8*)&hb[(size_t)nl * C_DIM + c16] = o1;
    *(bf16x8*)&hb[(size_t)nl * C_DIM + c16 + 8] = o2;
}

// ------- fused prep: convert 4 weight matrices fp32->bf16 + pack qk bias -------
__global__ __launch_bounds__(256) void prep_kernel(const float* __restrict__ qw,
                                                   const float* __restrict__ kw,
                                                   const float* __restrict__ vw,
                                                   const float* __restrict__ pw,
                                                   const float* __restrict__ qb,
                                                   const float* __restrict__ kb,
                                                   __bf16* __restrict__ wqk,
                                                   __bf16* __restrict__ wv,
                                                   __bf16* __restrict__ wp,
                                                   float* __restrict__ qkb) {
    int bi = blockIdx.x;
    int t = threadIdx.x;
    if (bi == 1024) {
        int i = t * 4;
#pragma unroll
        for (int e = 0; e < 4; ++e)
            qkb[i + e] = (i + e < 512) ? qb[i + e] : kb[i + e - 512];
        return;
    }
    const float* src;
    __bf16* dst;
    int blk = bi & 255;
    if (bi < 256)       { src = qw; dst = wqk; }
    else if (bi < 512)  { src = kw; dst = wqk + 262144; }
    else if (bi < 768)  { src = vw; dst = wv; }
    else                { src = pw; dst = wp; }
    int i = blk * 256 + t;
    float4 v = ((const float4*)src)[i];
    bf16x4 o;
    o[0] = (__bf16)v.x; o[1] = (__bf16)v.y; o[2] = (__bf16)v.z; o[3] = (__bf16)v.w;
    ((bf16x4*)dst)[i] = o;
}

// ------- softmax: one wave per row of 1024 bf16, in place, no LDS -------
__global__ __launch_bounds__(256) void softmax_bf16(__bf16* __restrict__ S) {
    int row = blockIdx.x * 4 + (threadIdx.x >> 6);
    int lane = threadIdx.x & 63;
    __bf16* p = S + (size_t)row * N_SP + lane * 16;
    bf16x8 v0 = *(bf16x8*)p;
    bf16x8 v1 = *(bf16x8*)(p + 8);
    float f[16];
#pragma unroll
    for (int e = 0; e < 8; ++e) { f[e] = (float)v0[e]; f[8 + e] = (float)v1[e]; }
    float m = f[0];
#pragma unroll
    for (int e = 1; e < 16; ++e) m = fmaxf(m, f[e]);
    for (int off = 32; off > 0; off >>= 1) m = fmaxf(m, __shfl_xor(m, off));
    float s = 0.f;
#pragma unroll
    for (int e = 0; e < 16; ++e) { f[e] = __expf(f[e] - m); s += f[e]; }
    for (int off = 32; off > 0; off >>= 1) s += __shfl_xor(s, off);
    float inv = 1.f / s;
#pragma unroll
    for (int e = 0; e < 8; ++e) { v0[e] = (__bf16)(f[e] * inv); v1[e] = (__bf16)(f[8 + e] * inv); }
    *(bf16x8*)p = v0;
    *(bf16x8*)(p + 8) = v1;
}

// ============ 128x128 8-wave GEMM, BK=64, dbuf 64KB LDS -> 2 blocks/CU ============
// C[M][N] = A[M][*] * BT[N][*]^T, bf16 in, fp32 acc. Wave-tile 32x64 (4x2 wave grid).
// Loop: issue STG(next buf) -> WAITV(4) (counted; prev buf landed) -> BAR ->
// reads+MFMA -> BAR. Cross-block TLP (2 blocks/CU) hides drains/barriers.
// EPI: 0 bf16; 1 bf16+bias[col]; 2 bf16+bias[row]; 4 f32+bias[row]+resid; 5 bf16*scale
#define WAITV(n) asm volatile("s_waitcnt vmcnt(" #n ")" ::: "memory")
#define BAR() __builtin_amdgcn_s_barrier()

template <int M, int N, int K, int LDA, int LDB, int EPI>
__global__ __launch_bounds__(512, 4) void gemm2b(const __bf16* __restrict__ A, size_t sA,
                                                 const __bf16* __restrict__ BT, size_t sB,
                                                 void* __restrict__ Y, size_t sY,
                                                 const float* __restrict__ bias,
                                                 const float* __restrict__ resid, size_t sR,
                                                 float scale) {
    static_assert(M % 128 == 0 && N % 128 == 0 && K % 64 == 0, "shape");
    constexpr int GX = N / 128, GY = M / 128, NT = K / 64;
    __shared__ __align__(16) __bf16 lds[2][2][8192];   // [buf][A/B][128 rows x 64 k]

    const int tid = threadIdx.x;
    const int w = tid >> 6, lane = tid & 63;
    const int wm = w >> 1, wn = w & 1;                 // 4 x 2 wave grid
    const int lrow = lane & 15, koct = lane >> 4;

    const int nwg = gridDim.x;
    const int wg = ((int)blockIdx.x & 7) * (nwg >> 3) + ((int)blockIdx.x >> 3);
    const int bz = wg / (GX * GY);
    const int rem = wg - bz * (GX * GY);
    const int bm = (rem / GX) * 128, bn = (rem % GX) * 128;

    const __bf16* Ab = A + (size_t)bz * sA;
    const __bf16* Bb = BT + (size_t)bz * sB;

    // staging: thread -> row tid>>3 (call0) / +64 (call1); source k pre-swizzled
    const int srow = tid >> 3;
    const int kswz = ((tid & 7) ^ (srow & 7)) * 8;
    const __bf16* srcA = Ab + (size_t)(bm + srow) * LDA + kswz;
    const __bf16* srcB = Bb + (size_t)(bn + srow) * LDB + kswz;

#define STG(buf, kt) do { \
    gload16(srcA + (size_t)(kt) * 64,                      &lds[buf][0][w * 512]); \
    gload16(srcA + (size_t)64 * LDA + (size_t)(kt) * 64,   &lds[buf][0][4096 + w * 512]); \
    gload16(srcB + (size_t)(kt) * 64,                      &lds[buf][1][w * 512]); \
    gload16(srcB + (size_t)64 * LDB + (size_t)(kt) * 64,   &lds[buf][1][4096 + w * 512]); \
} while (0)

    // fragment reads (read side of swizzle involution)
    const int ks0 = (koct ^ (lrow & 7)) * 8;
    const int ks1 = ks0 ^ 32;
    const int aoff = (wm * 32 + lrow) * 64;
    const int boff = (wn * 64 + lrow) * 64;

    bf16x8 aF[2][2], bF[2][2];
    f32x4 acc[2][4];
#pragma unroll
    for (int i = 0; i < 2; ++i)
#pragma unroll
        for (int j = 0; j < 4; ++j) acc[i][j] = (f32x4){0.f, 0.f, 0.f, 0.f};

#define RD_A(ct) do { _Pragma("unroll") for (int i = 0; i < 2; ++i) { \
    aF[i][0] = *(const bf16x8*)&lds[ct][0][aoff + i * 1024 + ks0]; \
    aF[i][1] = *(const bf16x8*)&lds[ct][0][aoff + i * 1024 + ks1]; } } while (0)
#define RD_B(ct, j0) do { _Pragma("unroll") for (int j = 0; j < 2; ++j) { \
    bF[j][0] = *(const bf16x8*)&lds[ct][1][boff + ((j0) + j) * 1024 + ks0]; \
    bF[j][1] = *(const bf16x8*)&lds[ct][1][boff + ((j0) + j) * 1024 + ks1]; } } while (0)

#define MM8(J0) do { \
    __builtin_amdgcn_s_setprio(1); \
    _Pragma("unroll") for (int k = 0; k < 2; ++k) \
    _Pragma("unroll") for (int i = 0; i < 2; ++i) \
    _Pragma("unroll") for (int j = 0; j < 2; ++j) \
        acc[i][(J0) + j] = __builtin_amdgcn_mfma_f32_16x16x32_bf16( \
            aF[i][k], bF[j][k], acc[i][(J0) + j], 0, 0, 0); \
    __builtin_amdgcn_s_setprio(0); \
} while (0)

    STG(0, 0);                       // prologue: 4 gloads in flight

#pragma unroll 1
    for (int t = 0; t < NT; ++t) {
        const int cur = t & 1;
        if (t + 1 < NT) {
            STG(cur ^ 1, t + 1);     // 8 in flight
            WAITV(4);                // oldest 4 (cur buf) landed
        } else {
            WAITV(0);
        }
        BAR();                       // all waves' cur-buf stages visible
        RD_A(cur);
        RD_B(cur, 0);
        MM8(0);
        RD_B(cur, 2);
        MM8(2);
        BAR();                       // cur buf free for overwrite next iter
    }

    // epilogue: C/D layout col=lane&15, row=koct*4+reg
    float* Yf = (float*)Y + (size_t)bz * sY;
    __bf16* Yh = (__bf16*)Y + (size_t)bz * sY;
    const float* Rb = (EPI == 4) ? (resid + (size_t)bz * sR) : nullptr;
#pragma unroll
    for (int i = 0; i < 2; ++i)
#pragma unroll
        for (int r = 0; r < 4; ++r) {
            int grow = bm + wm * 32 + i * 16 + koct * 4 + r;
            float brv = (EPI == 2 || EPI == 4) ? bias[grow] : 0.f;
#pragma unroll
            for (int j = 0; j < 4; ++j) {
                int gcol = bn + wn * 64 + j * 16 + lrow;
                float vv = acc[i][j][r];
                if (EPI == 1) vv += bias[gcol];
                if (EPI == 2 || EPI == 4) vv += brv;
                if (EPI == 5) vv *= scale;
                size_t yi = (size_t)grow * N + gcol;
                if (EPI == 4) {
                    Yf[yi] = vv + Rb[yi];
                } else {
                    Yh[yi] = (__bf16)vv;
                }
            }
        }
#undef STG
#undef RD_A
#undef RD_B
#undef MM8
}

extern "C" void kernel_launch(void* const* d_in, const int* in_sizes, int n_in,
                              void* d_out, int out_size, void* d_ws, size_t ws_size,
                              hipStream_t stream) {
    const float* x      = (const float*)d_in[0];
    const float* norm_w = (const float*)d_in[1];
    const float* norm_b = (const float*)d_in[2];
    const float* q_w    = (const float*)d_in[3];
    const float* q_b    = (const float*)d_in[4];
    const float* k_w    = (const float*)d_in[5];
    const float* k_b    = (const float*)d_in[6];
    const float* v_w    = (const float*)d_in[7];
    const float* v_b    = (const float*)d_in[8];
    const float* proj_w = (const float*)d_in[9];
    const float* proj_b = (const float*)d_in[10];
    float* out = (float*)d_out;

    const size_t ELEM = (size_t)N_SP * C_DIM;            // 524288
    const size_t QK   = (size_t)N_SP * 1024;             // 1048576
    char* ws = (char*)d_ws;
    __bf16* hT  = (__bf16*)ws;                           // 32MB, reused as Ot
    __bf16* qkT = (__bf16*)(ws + ((size_t)32 << 20));    // 64MB: [b][n][q||k]
    __bf16* wqk = (__bf16*)(ws + ((size_t)96 << 20));    // 1MB  [1024][512]
    __bf16* wv  = (__bf16*)(ws + ((size_t)97 << 20));
    __bf16* wp  = wv + 262144;
    float* qkb  = (float*)(ws + ((size_t)98 << 20));
    float* stats = qkb + 1024;
    size_t sbase = ((size_t)99 << 20);
    __bf16* S = (__bf16*)(ws + sbase);                   // chunk x [1024][1024] bf16
    __bf16* v  = (__bf16*)d_out;                         // V lives in d_out until proj
    __bf16* Ot = hT;

    int chunk = (int)((ws_size - sbase) >> 21);          // 2MB per batch of S
    if (chunk > B_DIM) chunk = B_DIM;
    if (chunk < 1) chunk = 1;

    gn_stats_kernel<<<B_DIM * GROUPS, 256, 0, stream>>>(x, stats);
    gn_apply_t_kernel<<<dim3(16, 8, B_DIM), 256, 0, stream>>>(x, stats, norm_w, norm_b, hT);

    prep_kernel<<<1025, 256, 0, stream>>>(q_w, k_w, v_w, proj_w, q_b, k_b,
                                          wqk, wv, wp, qkb);

    // qkT[n][0..1023] = hT[n][:] x (wq||wk)^T + (q_b||k_b)   (M = 32*1024 rows)
    gemm2b<32768, 1024, 512, 512, 512, 1><<<2048, 512, 0, stream>>>(
        hT, 0, wqk, 0, qkT, 0, qkb, nullptr, 0, 1.f);
    // v[b][oc][n] = wv[oc][:] x hT[b][n][:] + v_b[oc]
    gemm2b<512, 1024, 512, 512, 512, 2><<<1024, 512, 0, stream>>>(
        wv, 0, hT, ELEM, v, ELEM, v_b, nullptr, 0, 1.f);

    const float scale = 0.044194173824159216f;  // 512^-0.5
    for (int b0 = 0; b0 < B_DIM; b0 += chunk) {
        int nb = (b0 + chunk <= B_DIM) ? chunk : (B_DIM - b0);
        // S[i][j] = bf16( scale * sum_c qT[i][c] kT[j][c] )
        gemm2b<1024, 1024, 512, 1024, 1024, 5><<<64 * nb, 512, 0, stream>>>(
            qkT + (size_t)b0 * QK, QK, qkT + (size_t)b0 * QK + 512, QK,
            S, QK, nullptr, nullptr, 0, scale);
        softmax_bf16<<<nb * N_SP / 4, 256, 0, stream>>>(S);
        // Ot[i][c] = sum_j P[i][j] v[c][j]
        gemm2b<1024, 512, 1024, 1024, 1024, 0><<<32 * nb, 512, 0, stream>>>(
            S, QK, v + (size_t)b0 * ELEM, ELEM,
            Ot + (size_t)b0 * ELEM, ELEM, nullptr, nullptr, 0, 1.f);
    }

    // out[b][oc][n] = wp[oc][:] x Ot[b][n][:] + proj_b[oc] + x[b][oc][n]
    gemm2b<512, 1024, 512, 512, 512, 4><<<1024, 512, 0, stream>>>(
        wp, 0, Ot, ELEM, out, ELEM, proj_b, x, ELEM, 1.f);
}

// Round 8
// 247.178 us; speedup vs baseline: 1.0381x; 1.0193x over previous
//
#include <hip/hip_runtime.h>
#include <cstdint>

#define B_DIM 32
#define C_DIM 512
#define N_SP 1024
#define GROUPS 32
#define CPG 16
#define EPS 1e-5f

typedef __attribute__((ext_vector_type(8))) __bf16 bf16x8;
typedef __attribute__((ext_vector_type(4))) __bf16 bf16x4;
typedef __attribute__((ext_vector_type(4))) float f32x4;

__device__ __forceinline__ void gload16(const void* g, void* l) {
    __builtin_amdgcn_global_load_lds(
        (__attribute__((address_space(1))) void*)(unsigned long long)(uintptr_t)g,
        (__attribute__((address_space(3))) void*)(unsigned int)(uintptr_t)l,
        16, 0, 0);
}

// ------- fused GroupNorm: stats + apply + transpose, one x read -------
// one block per (b,g): 16 ch x 1024. x[b][c][n] -> hT[b][n][c] bf16.
__global__ __launch_bounds__(256) void gn_fused_kernel(const float* __restrict__ x,
                                                       const float* __restrict__ w,
                                                       const float* __restrict__ bia,
                                                       __bf16* __restrict__ hT) {
    __shared__ float tile[16][1025];
    __shared__ float sw[16], sb[16];
    __shared__ float ls[4], lq[4];
    const int bb = blockIdx.x >> 5, g = blockIdx.x & 31;
    const int t = threadIdx.x;
    const float* xb = x + ((size_t)(bb * C_DIM + g * CPG)) * N_SP;

    float s = 0.f, sq = 0.f;
#pragma unroll
    for (int i = 0; i < 16; ++i) {
        int idx = t + 256 * i;            // 0..4095 float4s
        int row = idx >> 8, c4 = (idx & 255) * 4;
        float4 v = *(const float4*)&xb[(size_t)row * N_SP + c4];
        tile[row][c4 + 0] = v.x; tile[row][c4 + 1] = v.y;
        tile[row][c4 + 2] = v.z; tile[row][c4 + 3] = v.w;
        s  += v.x + v.y + v.z + v.w;
        sq += v.x * v.x + v.y * v.y + v.z * v.z + v.w * v.w;
    }
    for (int off = 32; off > 0; off >>= 1) {
        s  += __shfl_xor(s, off);
        sq += __shfl_xor(sq, off);
    }
    int wid = t >> 6;
    if ((t & 63) == 0) { ls[wid] = s; lq[wid] = sq; }
    __syncthreads();
    if (t < 16) {
        s  = ls[0] + ls[1] + ls[2] + ls[3];
        sq = lq[0] + lq[1] + lq[2] + lq[3];
        float mean = s / (float)(CPG * N_SP);
        float var  = sq / (float)(CPG * N_SP) - mean * mean;
        float rstd = rsqrtf(var + EPS);
        float scl = w[g * CPG + t] * rstd;
        sw[t] = scl;
        sb[t] = bia[g * CPG + t] - mean * scl;
    }
    __syncthreads();
    __bf16* hb = hT + ((size_t)bb * N_SP) * C_DIM + g * CPG;
#pragma unroll
    for (int i = 0; i < 4; ++i) {
        int n = t + 256 * i;
        bf16x8 o1, o2;
#pragma unroll
        for (int c = 0; c < 8; ++c) o1[c] = (__bf16)(tile[c][n] * sw[c] + sb[c]);
#pragma unroll
        for (int c = 0; c < 8; ++c) o2[c] = (__bf16)(tile[8 + c][n] * sw[8 + c] + sb[8 + c]);
        *(bf16x8*)&hb[(size_t)n * C_DIM] = o1;
        *(bf16x8*)&hb[(size_t)n * C_DIM + 8] = o2;
    }
}

// ------- fused prep: convert 4 weight matrices fp32->bf16 + pack qk bias -------
__global__ __launch_bounds__(256) void prep_kernel(const float* __restrict__ qw,
                                                   const float* __restrict__ kw,
                                                   const float* __restrict__ vw,
                                                   const float* __restrict__ pw,
                                                   const float* __restrict__ qb,
                                                   const float* __restrict__ kb,
                                                   __bf16* __restrict__ wqk,
                                                   __bf16* __restrict__ wv,
                                                   __bf16* __restrict__ wp,
                                                   float* __restrict__ qkb) {
    int bi = blockIdx.x;
    int t = threadIdx.x;
    if (bi == 1024) {
        int i = t * 4;
#pragma unroll
        for (int e = 0; e < 4; ++e)
            qkb[i + e] = (i + e < 512) ? qb[i + e] : kb[i + e - 512];
        return;
    }
    const float* src;
    __bf16* dst;
    int blk = bi & 255;
    if (bi < 256)       { src = qw; dst = wqk; }
    else if (bi < 512)  { src = kw; dst = wqk + 262144; }
    else if (bi < 768)  { src = vw; dst = wv; }
    else                { src = pw; dst = wp; }
    int i = blk * 256 + t;
    float4 v = ((const float4*)src)[i];
    bf16x4 o;
    o[0] = (__bf16)v.x; o[1] = (__bf16)v.y; o[2] = (__bf16)v.z; o[3] = (__bf16)v.w;
    ((bf16x4*)dst)[i] = o;
}

// ------- softmax: one wave per row of 1024 bf16, in place, no LDS -------
__global__ __launch_bounds__(256) void softmax_bf16(__bf16* __restrict__ S) {
    int row = blockIdx.x * 4 + (threadIdx.x >> 6);
    int lane = threadIdx.x & 63;
    __bf16* p = S + (size_t)row * N_SP + lane * 16;
    bf16x8 v0 = *(bf16x8*)p;
    bf16x8 v1 = *(bf16x8*)(p + 8);
    float f[16];
#pragma unroll
    for (int e = 0; e < 8; ++e) { f[e] = (float)v0[e]; f[8 + e] = (float)v1[e]; }
    float m = f[0];
#pragma unroll
    for (int e = 1; e < 16; ++e) m = fmaxf(m, f[e]);
    for (int off = 32; off > 0; off >>= 1) m = fmaxf(m, __shfl_xor(m, off));
    float s = 0.f;
#pragma unroll
    for (int e = 0; e < 16; ++e) { f[e] = __expf(f[e] - m); s += f[e]; }
    for (int off = 32; off > 0; off >>= 1) s += __shfl_xor(s, off);
    float inv = 1.f / s;
#pragma unroll
    for (int e = 0; e < 8; ++e) { v0[e] = (__bf16)(f[e] * inv); v1[e] = (__bf16)(f[8 + e] * inv); }
    *(bf16x8*)p = v0;
    *(bf16x8*)(p + 8) = v1;
}

// ============ 128x128 8-wave GEMM, BK=64, dbuf, depth-1.5 prefetch ============
// C[M][N] = A[M][*] * BT[N][*]^T, bf16 in, fp32 acc.
// Per tile t (buf c=t&1): WAITV(4) [t's 4 loads landed; t+1's in flight] -> BAR ->
// 12 ds_read_b128 -> 8 MFMA(ks0) -> lgkmcnt(0) -> BAR [buf c free] ->
// STG(c, t+2) [issued ~1.7 tile-periods before its deadline] -> 8 MFMA(ks1).
// Never drains vmcnt to 0 in steady state. 64KB LDS -> 2 blocks/CU; VGPR<=128.
// EPI: 0 bf16; 2 bf16+bias[row]; 4 f32+bias[row]+resid; 5 bf16*scale;
//      6 bf16+bias[col], cols<512 -> Y (ld 512), cols>=512 -> Y2 (ld 512)
#define WAITV(n) asm volatile("s_waitcnt vmcnt(" #n ")" ::: "memory")
#define BAR() __builtin_amdgcn_s_barrier()

template <int M, int N, int K, int LDA, int LDB, int EPI>
__global__ __launch_bounds__(512, 4) void gemmP(const __bf16* __restrict__ A, size_t sA,
                                                const __bf16* __restrict__ BT, size_t sB,
                                                void* __restrict__ Y, size_t sY,
                                                const float* __restrict__ bias,
                                                const float* __restrict__ resid, size_t sR,
                                                float scale, void* __restrict__ Y2) {
    static_assert(M % 128 == 0 && N % 128 == 0 && K % 128 == 0, "shape");
    constexpr int GX = N / 128, GY = M / 128, NT = K / 64;
    __shared__ __align__(16) __bf16 lds[2][2][8192];   // [buf][A/B][128 rows x 64 k]

    const int tid = threadIdx.x;
    const int w = tid >> 6, lane = tid & 63;
    const int wm = w >> 1, wn = w & 1;                 // 4 x 2 wave grid, tile 32x64
    const int lrow = lane & 15, koct = lane >> 4;

    const int nwg = gridDim.x;
    const int wg = ((int)blockIdx.x & 7) * (nwg >> 3) + ((int)blockIdx.x >> 3);
    const int bz = wg / (GX * GY);
    const int rem = wg - bz * (GX * GY);
    const int bm = (rem / GX) * 128, bn = (rem % GX) * 128;

    const __bf16* Ab = A + (size_t)bz * sA;
    const __bf16* Bb = BT + (size_t)bz * sB;

    // staging: thread -> row tid>>3 (chunk0) / +64 (chunk1); source k pre-swizzled
    const int srow = tid >> 3;
    const int kswz = ((tid & 7) ^ (srow & 7)) * 8;
    const __bf16* srcA = Ab + (size_t)(bm + srow) * LDA + kswz;
    const __bf16* srcB = Bb + (size_t)(bn + srow) * LDB + kswz;

#define STG(buf, kt) do { \
    gload16(srcA + (size_t)(kt) * 64,                      &lds[buf][0][w * 512]); \
    gload16(srcA + (size_t)64 * LDA + (size_t)(kt) * 64,   &lds[buf][0][4096 + w * 512]); \
    gload16(srcB + (size_t)(kt) * 64,                      &lds[buf][1][w * 512]); \
    gload16(srcB + (size_t)64 * LDB + (size_t)(kt) * 64,   &lds[buf][1][4096 + w * 512]); \
} while (0)

    // fragment reads (read side of the swizzle involution)
    const int ks0 = (koct ^ (lrow & 7)) * 8;
    const int ks1 = ks0 ^ 32;
    const int aoff = (wm * 32 + lrow) * 64;
    const int boff = (wn * 64 + lrow) * 64;

    bf16x8 aF[2][2], bF[4][2];
    f32x4 acc[2][4];
#pragma unroll
    for (int i = 0; i < 2; ++i)
#pragma unroll
        for (int j = 0; j < 4; ++j) acc[i][j] = (f32x4){0.f, 0.f, 0.f, 0.f};

#define RD_ALL(ct) do { \
    _Pragma("unroll") for (int i = 0; i < 2; ++i) { \
        aF[i][0] = *(const bf16x8*)&lds[ct][0][aoff + i * 1024 + ks0]; \
        aF[i][1] = *(const bf16x8*)&lds[ct][0][aoff + i * 1024 + ks1]; } \
    _Pragma("unroll") for (int j = 0; j < 4; ++j) { \
        bF[j][0] = *(const bf16x8*)&lds[ct][1][boff + j * 1024 + ks0]; \
        bF[j][1] = *(const bf16x8*)&lds[ct][1][boff + j * 1024 + ks1]; } \
} while (0)

#define MM8(KS) do { \
    __builtin_amdgcn_s_setprio(1); \
    _Pragma("unroll") for (int i = 0; i < 2; ++i) \
    _Pragma("unroll") for (int j = 0; j < 4; ++j) \
        acc[i][j] = __builtin_amdgcn_mfma_f32_16x16x32_bf16( \
            aF[i][KS], bF[j][KS], acc[i][j], 0, 0, 0); \
    __builtin_amdgcn_s_setprio(0); \
} while (0)

    // prologue: stage tiles 0 and 1 (8 loads in flight)
    STG(0, 0);
    STG(1, 1);

#pragma unroll 1
    for (int t = 0; t < NT; ++t) {
        const int c = t & 1;
        if (t < NT - 1) { WAITV(4); } else { WAITV(0); }
        BAR();                     // tile t's data visible to all waves
        RD_ALL(c);                 // 12 x ds_read_b128
        MM8(0);                    // ks0 half (compiler interleaves with read waits)
        asm volatile("s_waitcnt lgkmcnt(0)" ::: "memory");
        __builtin_amdgcn_sched_barrier(0);
        BAR();                     // all waves done reading buf c
        if (t + 2 < NT) STG(c, t + 2);   // deadline ~1.7 tile-periods away
        MM8(1);                    // ks1 half covers the stage issue
    }

    // epilogue: C/D layout col=lane&15, row=koct*4+reg
    float* Yf = (float*)Y + (size_t)bz * sY;
    __bf16* Yh = (__bf16*)Y + (size_t)bz * sY;
    const float* Rb = (EPI == 4) ? (resid + (size_t)bz * sR) : nullptr;
    __bf16* Y6 = (EPI == 6) ? ((bn < 512) ? (__bf16*)Y : (__bf16*)Y2) : nullptr;
#pragma unroll
    for (int i = 0; i < 2; ++i)
#pragma unroll
        for (int r = 0; r < 4; ++r) {
            int grow = bm + wm * 32 + i * 16 + koct * 4 + r;
            float brv = (EPI == 2 || EPI == 4) ? bias[grow] : 0.f;
#pragma unroll
            for (int j = 0; j < 4; ++j) {
                int gcol = bn + wn * 64 + j * 16 + lrow;
                float vv = acc[i][j][r];
                if (EPI == 6) vv += bias[gcol];
                if (EPI == 2 || EPI == 4) vv += brv;
                if (EPI == 5) vv *= scale;
                if (EPI == 4) {
                    size_t yi = (size_t)grow * N + gcol;
                    Yf[yi] = vv + Rb[yi];
                } else if (EPI == 6) {
                    Y6[(size_t)grow * 512 + (gcol & 511)] = (__bf16)vv;
                } else {
                    Yh[(size_t)grow * N + gcol] = (__bf16)vv;
                }
            }
        }
#undef STG
#undef RD_ALL
#undef MM8
}

extern "C" void kernel_launch(void* const* d_in, const int* in_sizes, int n_in,
                              void* d_out, int out_size, void* d_ws, size_t ws_size,
                              hipStream_t stream) {
    const float* x      = (const float*)d_in[0];
    const float* norm_w = (const float*)d_in[1];
    const float* norm_b = (const float*)d_in[2];
    const float* q_w    = (const float*)d_in[3];
    const float* q_b    = (const float*)d_in[4];
    const float* k_w    = (const float*)d_in[5];
    const float* k_b    = (const float*)d_in[6];
    const float* v_w    = (const float*)d_in[7];
    const float* v_b    = (const float*)d_in[8];
    const float* proj_w = (const float*)d_in[9];
    const float* proj_b = (const float*)d_in[10];
    float* out = (float*)d_out;

    const size_t ELEM = (size_t)N_SP * C_DIM;            // 524288 elems = 1MB bf16
    const size_t QK   = (size_t)N_SP * N_SP;             // 1048576
    char* ws = (char*)d_ws;
    __bf16* hT  = (__bf16*)ws;                           // 32MB [b][n][c], reused as Ot
    __bf16* qT  = (__bf16*)(ws + ((size_t)32 << 20));    // 32MB [b][n][512]
    __bf16* kT  = (__bf16*)(ws + ((size_t)64 << 20));    // 32MB [b][n][512]
    __bf16* wqk = (__bf16*)(ws + ((size_t)96 << 20));    // 1MB [1024][512]
    __bf16* wv  = (__bf16*)(ws + ((size_t)97 << 20));    // 0.5MB
    __bf16* wp  = wv + 262144;                           // 0.5MB
    float* qkb  = (float*)(ws + ((size_t)98 << 20));     // 4KB
    size_t sbase = ((size_t)99 << 20);
    __bf16* S = (__bf16*)(ws + sbase);                   // chunk x [1024][1024] bf16
    __bf16* v  = (__bf16*)d_out;                         // V lives in d_out until proj
    __bf16* Ot = hT;

    int chunk = (int)((ws_size - sbase) >> 21);          // 2MB per batch of S
    if (chunk > B_DIM) chunk = B_DIM;
    if (chunk < 1) chunk = 1;

    gn_fused_kernel<<<B_DIM * GROUPS, 256, 0, stream>>>(x, norm_w, norm_b, hT);
    prep_kernel<<<1025, 256, 0, stream>>>(q_w, k_w, v_w, proj_w, q_b, k_b,
                                          wqk, wv, wp, qkb);

    // qT[n][oc] / kT[n][oc] = hT[n][:] x (wq||wk)^T + bias, split outputs
    gemmP<32768, 1024, 512, 512, 512, 6><<<2048, 512, 0, stream>>>(
        hT, 0, wqk, 0, qT, 0, qkb, nullptr, 0, 1.f, kT);
    // v[b][oc][n] = wv[oc][:] x hT[b][n][:] + v_b[oc]
    gemmP<512, 1024, 512, 512, 512, 2><<<1024, 512, 0, stream>>>(
        wv, 0, hT, ELEM, v, ELEM, v_b, nullptr, 0, 1.f, nullptr);

    const float scale = 0.044194173824159216f;  // 512^-0.5
    for (int b0 = 0; b0 < B_DIM; b0 += chunk) {
        int nb = (b0 + chunk <= B_DIM) ? chunk : (B_DIM - b0);
        // S[i][j] = bf16( scale * sum_c qT[i][c] kT[j][c] )
        gemmP<1024, 1024, 512, 512, 512, 5><<<64 * nb, 512, 0, stream>>>(
            qT + (size_t)b0 * ELEM, ELEM, kT + (size_t)b0 * ELEM, ELEM,
            S, QK, nullptr, nullptr, 0, scale, nullptr);
        softmax_bf16<<<nb * N_SP / 4, 256, 0, stream>>>(S);
        // Ot[i][c] = sum_j P[i][j] v[c][j]
        gemmP<1024, 512, 1024, 1024, 1024, 0><<<32 * nb, 512, 0, stream>>>(
            S, QK, v + (size_t)b0 * ELEM, ELEM,
            Ot + (size_t)b0 * ELEM, ELEM, nullptr, nullptr, 0, 1.f, nullptr);
    }

    // out[b][oc][n] = wp[oc][:] x Ot[b][n][:] + proj_b[oc] + x[b][oc][n]
    gemmP<512, 1024, 512, 512, 512, 4><<<1024, 512, 0, stream>>>(
        wp, 0, Ot, ELEM, out, ELEM, proj_b, x, ELEM, 1.f, nullptr);
}